// Round 1
// baseline (191.332 us; speedup 1.0000x reference)
//
#include <hip/hip_runtime.h>

typedef _Float16 f16x8 __attribute__((ext_vector_type(8)));
typedef float    f32x4 __attribute__((ext_vector_type(4)));

#define N_CTX 16384
#define N_Q   4096
#define DIM   100

static __device__ __forceinline__ unsigned short f2h_bits(float f) {
    union { _Float16 h; unsigned short u; } v;
    v.h = (_Float16)f;
    return v.u;
}

// ---------------- prep kernels ----------------

// one thread per question row j: t[j] = q_j . w2 ; qb[j][0:128] = fp16(q_j) padded
__global__ void prepQ(const float* __restrict__ q, const float* __restrict__ ker,
                      unsigned short* __restrict__ qb, float* __restrict__ t) {
    int j = blockIdx.x * 256 + threadIdx.x;
    if (j >= N_Q) return;
    const float* row = q + (size_t)j * DIM;
    unsigned short* orow = qb + (size_t)j * 128;
    float acc = 0.f;
    for (int d = 0; d < DIM; ++d) {
        float v = row[d];
        acc += v * ker[100 + d];
        orow[d] = f2h_bits(v);
    }
    for (int d = DIM; d < 128; ++d) orow[d] = 0;
    t[j] = acc;
}

// transpose qb -> qT [112][4096] fp16
__global__ void prepQT(const unsigned short* __restrict__ qb, unsigned short* __restrict__ qT) {
    int j0 = blockIdx.x * 64;
    for (int idx = threadIdx.x; idx < 112 * 64; idx += 256) {
        int d = idx >> 6;
        int jj = idx & 63;
        qT[(size_t)d * N_Q + j0 + jj] = qb[(size_t)(j0 + jj) * 128 + d];
    }
}

// a[i] = c_i . w1
__global__ void prepA(const float* __restrict__ ctx, const float* __restrict__ ker,
                      float* __restrict__ a) {
    int i = blockIdx.x * 256 + threadIdx.x;
    if (i >= N_CTX) return;
    const float* row = ctx + (size_t)i * DIM;
    float acc = 0.f;
    for (int d = 0; d < DIM; ++d) acc += row[d] * ker[d];
    a[i] = acc;
}

// ---------------- main fused attention ----------------
// grid 512 blocks x 256 thr. Block owns rows [i0, i0+32). Wave w sweeps j chunk
// [w*1024,(w+1)*1024) with online softmax; LDS split-K combine writes
// G[:,0:300] and mfull[i] = a_i + max_j S_ij.
__global__ __launch_bounds__(256, 2) void attn_main(
    const unsigned short* __restrict__ qb, const unsigned short* __restrict__ qT,
    const float* __restrict__ t, const float* __restrict__ a,
    const float* __restrict__ ctx, const float* __restrict__ ker,
    float* __restrict__ G, float* __restrict__ mfull)
{
    __shared__ float smU[4][112][32];
    __shared__ float smM[4][32];
    __shared__ float smL[4][32];

    const int i0   = blockIdx.x * 32;
    const int tid  = threadIdx.x;
    const int w    = tid >> 6;
    const int lane = tid & 63;
    const int g    = lane >> 4;   // 16-lane group 0..3
    const int c    = lane & 15;   // column within fragment

    // Build cb B-fragments in-register: B[k=d][n=i] = (c*w3)[i][d]
    // lane holds cb[i0 + it*16 + c][kk*32 + 8g + e]
    f16x8 cbF[2][4];
    #pragma unroll
    for (int it = 0; it < 2; ++it) {
        const float* crow = ctx + (size_t)(i0 + it * 16 + c) * DIM;
        #pragma unroll
        for (int kk = 0; kk < 4; ++kk) {
            f16x8 f;
            #pragma unroll
            for (int e = 0; e < 8; ++e) {
                int d = kk * 32 + 8 * g + e;
                float v = (d < DIM) ? crow[d] * ker[200 + d] : 0.f;
                f[e] = (_Float16)v;
            }
            cbF[it][kk] = f;
        }
    }

    f32x4 U[7][2] = {};           // U^T accumulator: row=d-local(4g+r), col=i(c)
    float m0 = -INFINITY, m1 = -INFINITY;
    float l0 = 0.f, l1 = 0.f;

    int j0 = w * 1024;
    for (int s = 0; s < 32; ++s, j0 += 32) {
        f32x4 tA = *reinterpret_cast<const f32x4*>(t + j0 + 4 * g);
        f32x4 tB = *reinterpret_cast<const f32x4*>(t + j0 + 16 + 4 * g);

        // S^T tiles: C[m=j-local][n=i] ; A = q rows, B = cb fragments
        f32x4 sc[2][2] = {};
        #pragma unroll
        for (int js = 0; js < 2; ++js) {
            #pragma unroll
            for (int kk = 0; kk < 4; ++kk) {
                f16x8 aq = *reinterpret_cast<const f16x8*>(
                    qb + (size_t)(j0 + js * 16 + c) * 128 + kk * 32 + 8 * g);
                sc[js][0] = __builtin_amdgcn_mfma_f32_16x16x32_f16(aq, cbF[0][kk], sc[js][0], 0, 0, 0);
                sc[js][1] = __builtin_amdgcn_mfma_f32_16x16x32_f16(aq, cbF[1][kk], sc[js][1], 0, 0, 0);
            }
        }

        f16x8 pf[2];
        #pragma unroll
        for (int it = 0; it < 2; ++it) {
            float& m  = it ? m1 : m0;
            float& lp = it ? l1 : l0;
            float p0[4], p1[4];
            float tm = -INFINITY;
            #pragma unroll
            for (int r = 0; r < 4; ++r) {
                p0[r] = sc[0][it][r] + tA[r];
                p1[r] = sc[1][it][r] + tB[r];
                tm = fmaxf(tm, fmaxf(p0[r], p1[r]));
            }
            // row (= column c of S^T) max across the 4 groups
            tm = fmaxf(tm, __shfl_xor(tm, 16, 64));
            tm = fmaxf(tm, __shfl_xor(tm, 32, 64));
            float nm = fmaxf(m, tm);
            float scale = __expf(m - nm);
            m = nm;
            float ps = 0.f;
            #pragma unroll
            for (int r = 0; r < 4; ++r) {
                p0[r] = __expf(p0[r] - nm);
                p1[r] = __expf(p1[r] - nm);
                ps += p0[r] + p1[r];
            }
            lp = lp * scale + ps;
            #pragma unroll
            for (int dt = 0; dt < 7; ++dt) U[dt][it] *= scale;

            // Relayout P (S^T C-layout) -> PV B-operand: lane needs P[i=c][j=8g+e]
            f16x8 pv;
            #pragma unroll
            for (int e = 0; e < 8; ++e) {
                int sl = ((2 * (g & 1) + (e >> 2)) << 4) | c;
                float v0 = __shfl(p0[e & 3], sl, 64);
                float v1 = __shfl(p1[e & 3], sl, 64);
                pv[e] = (_Float16)(g >= 2 ? v1 : v0);
            }
            pf[it] = pv;
        }

        // PV: U^T[d][i] += V^T[d][j] * P^T[j][i] ; A from qT rows (contiguous)
        const unsigned short* qTbase = qT + (size_t)c * N_Q + j0 + 8 * g;
        #pragma unroll
        for (int dt = 0; dt < 7; ++dt) {
            f16x8 av = *reinterpret_cast<const f16x8*>(qTbase + (size_t)dt * 16 * N_Q);
            U[dt][0] = __builtin_amdgcn_mfma_f32_16x16x32_f16(av, pf[0], U[dt][0], 0, 0, 0);
            U[dt][1] = __builtin_amdgcn_mfma_f32_16x16x32_f16(av, pf[1], U[dt][1], 0, 0, 0);
        }
    }

    // finalize per-wave partial row sums (across the 4 groups)
    l0 += __shfl_xor(l0, 16, 64); l0 += __shfl_xor(l0, 32, 64);
    l1 += __shfl_xor(l1, 16, 64); l1 += __shfl_xor(l1, 32, 64);

    // stash partials in LDS
    #pragma unroll
    for (int it = 0; it < 2; ++it)
        #pragma unroll
        for (int dt = 0; dt < 7; ++dt)
            #pragma unroll
            for (int r = 0; r < 4; ++r)
                smU[w][dt * 16 + 4 * g + r][it * 16 + c] = U[dt][it][r];
    if (g == 0) {
        smM[w][0 * 16 + c]  = m0; smM[w][1 * 16 + c]  = m1;
        smL[w][0 * 16 + c]  = l0; smL[w][1 * 16 + c]  = l1;
    }
    __syncthreads();

    // split-K combine + epilogue (G cols 0..299, mfull)
    {
        int i32 = tid & 31;
        int seg = tid >> 5;          // 8 segments x 14 d's = 112
        float M = -INFINITY;
        float mw[4];
        #pragma unroll
        for (int ww = 0; ww < 4; ++ww) { mw[ww] = smM[ww][i32]; M = fmaxf(M, mw[ww]); }
        float ew[4];
        float L = 0.f;
        #pragma unroll
        for (int ww = 0; ww < 4; ++ww) { ew[ww] = __expf(mw[ww] - M); L += smL[ww][i32] * ew[ww]; }
        int row = i0 + i32;
        if (seg == 0) mfull[row] = a[row] + M;
        float invL = 1.f / L;
        for (int k = 0; k < 14; ++k) {
            int d = seg * 14 + k;
            if (d < DIM) {
                float u = 0.f;
                #pragma unroll
                for (int ww = 0; ww < 4; ++ww) u += smU[ww][d][i32] * ew[ww];
                float ua = u * invL;
                float cv = ctx[(size_t)row * DIM + d];
                size_t base = (size_t)row * 400;
                G[base + d]       = cv;
                G[base + 100 + d] = ua;
                G[base + 200 + d] = ua * cv;
            }
        }
    }
}

// ---------------- b-softmax + h ----------------

// per-block redundant M,Z over mfull; block accumulates 64 rows of b_i * c_i
__global__ void kernel_h(const float* __restrict__ mfull, const float* __restrict__ ctx,
                         float* __restrict__ hp) {
    __shared__ float sm[256];
    int t = threadIdx.x;
    float v = -INFINITY;
    for (int i = t; i < N_CTX; i += 256) v = fmaxf(v, mfull[i]);
    sm[t] = v; __syncthreads();
    for (int s = 128; s > 0; s >>= 1) { if (t < s) sm[t] = fmaxf(sm[t], sm[t + s]); __syncthreads(); }
    float M = sm[0];
    __syncthreads();
    float z = 0.f;
    for (int i = t; i < N_CTX; i += 256) z += __expf(mfull[i] - M);
    sm[t] = z; __syncthreads();
    for (int s = 128; s > 0; s >>= 1) { if (t < s) sm[t] += sm[t + s]; __syncthreads(); }
    float Z = sm[0];
    if (t < DIM) {
        int i0 = blockIdx.x * 64;
        float acc = 0.f;
        for (int r = 0; r < 64; ++r)
            acc += __expf(mfull[i0 + r] - M) * ctx[(size_t)(i0 + r) * DIM + t];
        hp[t * 256 + blockIdx.x] = acc / Z;
    }
}

__global__ void kernel_hred(const float* __restrict__ hp, float* __restrict__ h) {
    __shared__ float sm[4][128];
    int t = threadIdx.x;
    int d = t & 127, rep = t >> 7;
    float s = 0.f;
    if (d < DIM) for (int b = 0; b < 64; ++b) s += hp[d * 256 + rep * 64 + b];
    sm[rep][d] = s;
    __syncthreads();
    if (rep == 0 && d < DIM) h[d] = sm[0][d] + sm[1][d] + sm[2][d] + sm[3][d];
}

// G[:,300:400] = c * h
__global__ void kernel_g4(const float* __restrict__ ctx, const float* __restrict__ h,
                          float* __restrict__ G) {
    int idx = blockIdx.x * 256 + threadIdx.x;
    if (idx >= N_CTX * DIM) return;
    int i = idx / DIM;
    int d = idx - i * DIM;
    G[(size_t)i * 400 + 300 + d] = ctx[idx] * h[d];
}

// ---------------- launcher ----------------

extern "C" void kernel_launch(void* const* d_in, const int* in_sizes, int n_in,
                              void* d_out, int out_size, void* d_ws, size_t ws_size,
                              hipStream_t stream) {
    const float* ctx = (const float*)d_in[0];
    const float* q   = (const float*)d_in[1];
    const float* ker = (const float*)d_in[2];
    float* G = (float*)d_out;

    char* ws = (char*)d_ws;
    unsigned short* qb    = (unsigned short*)(ws);                 // 1,048,576
    unsigned short* qT    = (unsigned short*)(ws + 1048576);       //   917,504
    float*          t     = (float*)(ws + 1966080);                //    16,384
    float*          a     = (float*)(ws + 1982464);                //    65,536
    float*          mfull = (float*)(ws + 2048000);                //    65,536
    float*          hp    = (float*)(ws + 2113536);                //   102,400
    float*          h     = (float*)(ws + 2215936);                //       400

    prepQ<<<dim3(16), dim3(256), 0, stream>>>(q, ker, qb, t);
    prepQT<<<dim3(64), dim3(256), 0, stream>>>(qb, qT);
    prepA<<<dim3(64), dim3(256), 0, stream>>>(ctx, ker, a);
    attn_main<<<dim3(512), dim3(256), 0, stream>>>(qb, qT, t, a, ctx, ker, G, mfull);
    kernel_h<<<dim3(256), dim3(256), 0, stream>>>(mfull, ctx, hp);
    kernel_hred<<<dim3(1), dim3(512), 0, stream>>>(hp, h);
    kernel_g4<<<dim3(6400), dim3(256), 0, stream>>>(ctx, h, G);
}